// Round 1
// baseline (242.965 us; speedup 1.0000x reference)
//
#include <hip/hip_runtime.h>

// FlyHash-style sparse projection + per-row exact top-k threshold.
//
// Round 13: same algorithm as R12 (wave-parallel bracket-bin scan, zero-
// iteration list-select, LDS-recompute fallback, nontemporal stores), but
// TPB 1024->512 with FPT 10->20 and __launch_bounds__(512,4).
// Rationale: at (1024,4) only ONE block is resident per CU, so the LDS-
// gather/fold phase (~20us/CU) and the HBM store phase (~27us/CU) fully
// serialize. At 512 threads / <=128 VGPR, TWO blocks co-reside (2048 thr,
// 51.5 KB LDS), letting one block's phase-1 LDS gathers overlap the other
// block's phase-5 store drain. x4[20] = 80 persisted VGPRs + temps stays
// under the 128-VGPR cap (this is why (1024,8)'s 64-VGPR cap spilled and
// regressed, but (512,4) should not).
// Bit-exactness (absmax 0 through R12): serial f32 fold-left ascending ==
// ref einsum accumulation; threshold = an actual x value's bit pattern.
// Thread->feature map changes to f = tid + i*512 (bijection, used
// consistently in phases 1/3a/5) — per-feature arithmetic is unchanged.

typedef float f4 __attribute__((ext_vector_type(4)));

constexpr int IN_F   = 512;
constexpr int OUT_F  = 10240;
constexpr int TPB    = 512;
constexpr int ROWS   = 4;                 // batch rows per block
constexpr int FPT    = OUT_F / TPB;       // 20 features per thread
constexpr int NBINS  = 1024;              // per-row bins over [4,6), width 1/512
constexpr int NWAVES = TPB / 64;          // 8
constexpr int CAP    = 64;                // bracket-bin list capacity per row

static_assert(NBINS == 64 * 16, "wave scan assumes 16 bins per lane");
static_assert(TPB == IN_F, "staging assumes one f4 per thread");

// ---------------------------------------------------------------------------
// Kernel 1: extract sparse indices from dense W. One wave per W row.
// Emits indices ASCENDING (required for bit-exact fold-left downstream).
// ---------------------------------------------------------------------------
__global__ __launch_bounds__(256) void extract_idx(const float* __restrict__ W,
                                                   uint4* __restrict__ packed,
                                                   int out_f) {
  int row  = blockIdx.x * 4 + (threadIdx.x >> 6);
  int lane = threadIdx.x & 63;
  if (row >= out_f) return;

  const float* wr = W + (size_t)row * IN_F;
  unsigned long long masks[8];
#pragma unroll
  for (int c = 0; c < 8; ++c) {
    float v = wr[c * 64 + lane];
    masks[c] = __ballot(v != 0.0f);   // entries are exactly 0.0 or 1.0
  }
  if (lane == 0) {
    unsigned idx[6] = {IN_F, IN_F, IN_F, IN_F, IN_F, IN_F};  // pad -> zero slot
    int n = 0;
#pragma unroll
    for (int c = 0; c < 8; ++c) {
      unsigned long long m = masks[c];
      while (m && n < 6) {
        int b = __builtin_ctzll(m);
        idx[n++] = (unsigned)(c * 64 + b);
        m &= m - 1;
      }
    }
    uint4 r;
    r.x = idx[0] | (idx[1] << 16);
    r.y = idx[2] | (idx[3] << 16);
    r.z = idx[4] | (idx[5] << 16);
    r.w = (unsigned)n;
    packed[row] = r;
  }
}

// Serial fold of one row-component r (bit-identical to phase-1's fold).
__device__ __forceinline__ float row_val(const f4* in4, uint4 p, int r) {
  const float* b = (const float*)in4;
  float s = b[(p.x & 0xFFFFu) * 4 + r];
  s += b[(p.x >> 16) * 4 + r];
  s += b[(p.y & 0xFFFFu) * 4 + r];
  s += b[(p.y >> 16) * 4 + r];
  s += b[(p.z & 0xFFFFu) * 4 + r];
  s += b[(p.z >> 16) * 4 + r];
  return s;
}

// ---------------------------------------------------------------------------
// Kernel 2: 4 batch rows per block, 512 threads, x4[20] persisted (80 VGPR).
// Two blocks co-resident per CU -> gather phase overlaps store phase.
// ---------------------------------------------------------------------------
__global__ __launch_bounds__(TPB, 4) void fly_hash(const float* __restrict__ inp,
                                                   const uint4* __restrict__ packed,
                                                   const int* __restrict__ kptr,
                                                   float* __restrict__ out) {
  __shared__ f4    in4[IN_F + 1];       // 8.2 KB; [IN_F] = zero slot for pads
  __shared__ int   hist[ROWS * NBINS];  // 16 KB
  __shared__ int   wsum[NWAVES];
  __shared__ int   sh_bstar[ROWS], sh_above[ROWS], sh_n[ROWS], sh_cnt[ROWS];
  __shared__ float sh_list[ROWS][CAP];
  __shared__ float sh_thr[ROWS];
  __shared__ int   sh_need[ROWS];       // 1 -> fallback binary search

  const int tid  = threadIdx.x;
  const int lane = tid & 63;
  const int wid  = tid >> 6;
  const int row0 = blockIdx.x * ROWS;
  const int k    = *kptr;               // hash_length (32)

  // --- stage 4 input rows transposed into LDS (every thread stages 1 f4) --
  {
    const float* p = inp + (size_t)row0 * IN_F + tid;
    f4 v;
    v.x = p[0];
    v.y = p[IN_F];
    v.z = p[2 * IN_F];
    v.w = p[3 * IN_F];
    in4[tid] = v;                       // ds_write_b128, conflict-free
  }
  if (tid == 0) {
    f4 z = {0.0f, 0.0f, 0.0f, 0.0f};
    in4[IN_F] = z;
  }
  if (tid < ROWS) { sh_bstar[tid] = -1; sh_cnt[tid] = 0; }
  for (int i = tid; i < ROWS * NBINS; i += TPB) hist[i] = 0;
  __syncthreads();

  // --- phase 1: compute x (bit-exact serial fold-left) + histogram -------
  f4 x4[FPT];
#pragma unroll
  for (int i = 0; i < FPT; ++i) {
    uint4 r = packed[tid + i * TPB];
    f4 s = in4[r.x & 0xFFFFu];          // ds_read_b128: 4 rows per gather
    s += in4[r.x >> 16];
    s += in4[r.y & 0xFFFFu];
    s += in4[r.y >> 16];
    s += in4[r.z & 0xFFFFu];
    s += in4[r.z >> 16];
    x4[i] = s;
#pragma unroll
    for (int rr = 0; rr < ROWS; ++rr) {
      float v = s[rr];
      if (v >= 4.0f) {                  // top-32 of 10240 ~ 4.8; bin >=4 only
        int b = (int)((v - 4.0f) * 512.0f);    // EXACT key (Sterbenz + pow2)
        b = b > NBINS - 1 ? NBINS - 1 : b;
        atomicAdd(&hist[rr * NBINS + b], 1);
      }
    }
  }
  __syncthreads();

  // --- phase 2: wave-parallel bracket-bin search (wave r owns row r) -----
  // Lane L sums bins [16L, 16L+16); 6-step shfl suffix scan; crossing lane
  // walks its 16 bins descending to the exact bin. No internal barriers.
  if (wid < ROWS) {
    const int r = wid;
    const int base = r * NBINS + lane * 16;
    int csum = 0;
#pragma unroll
    for (int j = 0; j < 16; ++j) csum += hist[base + j];
    int s = csum;                       // inclusive suffix sum across lanes
#pragma unroll
    for (int off = 1; off < 64; off <<= 1) {
      int t = __shfl_down(s, off);
      if (lane + off < 64) s += t;
    }
    int s_next = __shfl_down(s, 1);     // suffix starting at lane+1
    if (lane == 63) s_next = 0;
    if (s >= k && s_next < k) {         // unique crossing chunk (if any)
      int acc = s_next;
      int bsel = lane * 16, abv = s_next;
      for (int b = lane * 16 + 15; b >= lane * 16; --b) {
        int h = hist[r * NBINS + b];
        if (acc + h >= k) { bsel = b; abv = acc; break; }
        acc += h;
      }
      sh_bstar[r] = bsel;
      sh_above[r] = abv;
      sh_n[r]     = hist[r * NBINS + bsel];
    }
  }
  __syncthreads();

  // --- phase 3a: collect bracket-bin members into per-row lists ----------
  {
    const int b0 = sh_bstar[0], b1 = sh_bstar[1];
    const int b2 = sh_bstar[2], b3 = sh_bstar[3];
#pragma unroll
    for (int i = 0; i < FPT; ++i) {
      f4 s = x4[i];
#pragma unroll
      for (int rr = 0; rr < ROWS; ++rr) {
        float v = s[rr];
        int bb = (rr == 0) ? b0 : (rr == 1) ? b1 : (rr == 2) ? b2 : b3;
        if (v >= 4.0f) {
          int b = (int)((v - 4.0f) * 512.0f);
          b = b > NBINS - 1 ? NBINS - 1 : b;
          if (b == bb) {
            int p = atomicAdd(&sh_cnt[rr], 1);
            if (p < CAP) sh_list[rr][p] = v;
          }
        }
      }
    }
  }
  __syncthreads();

  // --- phase 3b: wave r rank-selects the (k-above)-th largest in its list -
  if (wid < ROWS) {
    const int r   = wid;
    const int bst = sh_bstar[r];
    const int n   = (bst >= 0) ? sh_n[r] : CAP + 1;
    if (bst >= 0 && n <= CAP && sh_cnt[r] <= CAP) {
      const int j = k - sh_above[r];            // 1 <= j <= n
      float vl = (lane < n) ? sh_list[r][lane] : -1.0f;
      int cgt = 0, cge = 0;
      for (int m = 0; m < n; ++m) {
        float u = sh_list[r][m];                // broadcast LDS read
        cgt += (u > vl);
        cge += (u >= vl);
      }
      if (lane < n && cgt < j && cge >= j) sh_thr[r] = vl;  // exact k-th bits
      if (lane == 0) sh_need[r] = 0;
    } else {
      if (lane == 0) sh_need[r] = 1;            // overflow / no bracket
    }
  }
  __syncthreads();

  // --- phase 4: fallback (recomputes from LDS, never touches x4; rare) ---
#pragma unroll 1
  for (int r = 0; r < ROWS; ++r) {
    if (!sh_need[r]) continue;
    unsigned lo = 0u, hi = __float_as_uint(8.0f);
    while (lo < hi) {
      unsigned mid = lo + ((hi - lo + 1u) >> 1);
      float fm = __uint_as_float(mid);
      int c = 0;
      for (int i = 0; i < FPT; ++i) {
        uint4 p = packed[tid + i * TPB];
        c += (int)__popcll(__ballot(row_val(in4, p, r) >= fm));
      }
      if (lane == 0) wsum[wid] = c;
      __syncthreads();
      int tot = 0;
#pragma unroll
      for (int w = 0; w < NWAVES; ++w) tot += wsum[w];
      if (tot >= k) lo = mid; else hi = mid - 1u;
      __syncthreads();
    }
    if (tid == 0) sh_thr[r] = __uint_as_float(lo);
    __syncthreads();
  }
  const float t0 = sh_thr[0];
  const float t1 = sh_thr[1];
  const float t2 = sh_thr[2];
  const float t3 = sh_thr[3];

  // --- phase 5: thresholded writes, 4 coalesced nontemporal streams ------
  float* o0 = out + (size_t)(row0 + 0) * OUT_F;
  float* o1 = out + (size_t)(row0 + 1) * OUT_F;
  float* o2 = out + (size_t)(row0 + 2) * OUT_F;
  float* o3 = out + (size_t)(row0 + 3) * OUT_F;
#pragma unroll
  for (int i = 0; i < FPT; ++i) {
    int f = tid + i * TPB;
    f4 v = x4[i];
    __builtin_nontemporal_store((v.x >= t0) ? v.x : 0.0f, &o0[f]);
    __builtin_nontemporal_store((v.y >= t1) ? v.y : 0.0f, &o1[f]);
    __builtin_nontemporal_store((v.z >= t2) ? v.z : 0.0f, &o2[f]);
    __builtin_nontemporal_store((v.w >= t3) ? v.w : 0.0f, &o3[f]);
  }
}

// ---------------------------------------------------------------------------
extern "C" void kernel_launch(void* const* d_in, const int* in_sizes, int n_in,
                              void* d_out, int out_size, void* d_ws, size_t ws_size,
                              hipStream_t stream) {
  const float* inp = (const float*)d_in[0];
  const float* W   = (const float*)d_in[1];
  const int* kptr  = (const int*)d_in[2];
  float* out       = (float*)d_out;

  const int batch = in_sizes[0] / IN_F;   // 4096
  const int out_f = in_sizes[1] / IN_F;   // 10240

  uint4* packed = (uint4*)d_ws;           // 10240 * 16 B = 160 KB scratch

  hipLaunchKernelGGL(extract_idx, dim3((out_f + 3) / 4), dim3(256), 0, stream,
                     W, packed, out_f);
  hipLaunchKernelGGL(fly_hash, dim3(batch / ROWS), dim3(TPB), 0, stream,
                     inp, packed, kptr, out);
}